// Round 20
// baseline (248.305 us; speedup 1.0000x reference)
//
#include <hip/hip_runtime.h>
#include <hip/hip_bf16.h>

using bf16x8 = __attribute__((ext_vector_type(8))) short;
using f32x4  = __attribute__((ext_vector_type(4))) float;
using f16x2  = __attribute__((ext_vector_type(2))) _Float16;

#define ODE_NSTEP 1  // RK4 single step (bit-identical through nine halvings, r9-r19)

__device__ __forceinline__ unsigned short f2bf(float f) {
    unsigned int u = __float_as_uint(f);
    return (unsigned short)((u + 0x7fffu + ((u >> 16) & 1u)) >> 16);
}
__device__ __forceinline__ float bf2f(unsigned int s) {
    return __uint_as_float(s << 16);
}
__device__ __forceinline__ unsigned short f2h(float f) {
    _Float16 h = (_Float16)f;
    return __builtin_bit_cast(unsigned short, h);
}
__device__ __forceinline__ unsigned int packh(float lo, float hi) {
    return (unsigned int)f2h(lo) | ((unsigned int)f2h(hi) << 16);
}
__device__ __forceinline__ float fdot2u(unsigned int a, unsigned int b, float c) {
#if __has_builtin(__builtin_amdgcn_fdot2)
    return __builtin_amdgcn_fdot2(__builtin_bit_cast(f16x2, a),
                                  __builtin_bit_cast(f16x2, b), c, false);
#else
    f16x2 av = __builtin_bit_cast(f16x2, a), bv = __builtin_bit_cast(f16x2, b);
    return c + (float)av.x * (float)bv.x + (float)av.y * (float)bv.y;
#endif
}
__device__ __forceinline__ float fast_tanh(float xx) {
    float a = __expf(-2.f * fabsf(xx));
    float r = (1.f - a) / (1.f + a);
    return copysignf(r, xx);
}

// ---------------------------------------------------------------------------
// K0: weight repack (unchanged layouts).
// ---------------------------------------------------------------------------
__global__ void convert_kernel(const float* __restrict__ tW2, const float* __restrict__ tW3,
                               const float* __restrict__ bW1, const float* __restrict__ bW2,
                               const float* __restrict__ bW3, const float* __restrict__ bW4,
                               unsigned short* __restrict__ tW2T, unsigned short* __restrict__ tW3T,
                               unsigned int* __restrict__ W1u, unsigned int* __restrict__ W2u,
                               unsigned int* __restrict__ W3u, unsigned int* __restrict__ W4u) {
    int idx = blockIdx.x * blockDim.x + threadIdx.x;
    if (idx < 262144) {
        int cb = idx >> 13, rem = idx & 8191;
        int kb = rem >> 7, rem2 = rem & 127;
        int cl = rem2 >> 3, kl = rem2 & 7;
        int col = cb * 16 + cl, k = kb * 8 + kl;
        tW2T[idx] = f2bf(tW2[k * 512 + col]);
    } else if (idx < 327680) {
        int i = idx - 262144;
        int cb = i >> 13, rem = i & 8191;
        int kb = rem >> 7, rem2 = rem & 127;
        int cl = rem2 >> 3, kl = rem2 & 7;
        int col = cb * 16 + cl, k = kb * 8 + kl;
        tW3T[i] = f2bf(tW3[k * 128 + col]);
    } else if (idx < 344064) {
        int i = idx - 327680, kp = i >> 8, c = i & 255;
        W1u[i] = packh(bW1[(2 * kp) * 256 + c], bW1[(2 * kp + 1) * 256 + c]);
    } else if (idx < 409600) {
        int i = idx - 344064, kp = i >> 9, c = i & 511;
        W2u[i] = packh(bW2[(2 * kp) * 512 + c], bW2[(2 * kp + 1) * 512 + c]);
    } else if (idx < 475136) {
        int i = idx - 409600, kp = i >> 8, c = i & 255;
        W3u[i] = packh(bW3[(2 * kp) * 256 + c], bW3[(2 * kp + 1) * 256 + c]);
    } else if (idx < 491520) {
        int i = idx - 475136, kp = i >> 7, c = i & 127;
        W4u[i] = packh(bW4[(2 * kp) * 128 + c], bW4[(2 * kp + 1) * 128 + c]);
    }
}

// ---------------------------------------------------------------------------
// ODE body: ALL weights streamed from L2 (no AGPR, ~18.7KB LDS). ODE has ~7x
// slack (hidden under trunk), so residency no longer pays; frees occupancy.
// LDS: part@0 16KB | vq@16384 | h1q@16640 | h2h@17152 | h3q@18176..18688
// ---------------------------------------------------------------------------
__device__ __forceinline__ void ode_body(
    char* smem, int row,
    const float* __restrict__ x0,
    const unsigned int* __restrict__ gW1, const float* __restrict__ bb1,
    const unsigned int* __restrict__ gW2, const float* __restrict__ bb2,
    const unsigned int* __restrict__ gW3, const float* __restrict__ bb3,
    const unsigned int* __restrict__ gW4, const float* __restrict__ bb4,
    float* __restrict__ branch) {
    float* part = (float*)smem;
    unsigned int* vq  = (unsigned int*)(smem + 16384);
    unsigned int* h1q = (unsigned int*)(smem + 16640);
    unsigned short* h2h = (unsigned short*)(smem + 17152);
    unsigned int* h3q = (unsigned int*)(smem + 18176);

    const int t = threadIdx.x;
    const int jA = t & 255, khA = t >> 8;     // L1: col, k-half (wave-uniform)
    const int kq16 = t >> 5, g32 = t & 31;    // L3
    const int jD = t & 127, kqD = t >> 7;     // L4 (kqD wave-uniform)

    float2 b1p = make_float2(0.f, 0.f), b3p = b1p, b4p = b1p;
    if (t < 128) b1p = ((const float2*)bb1)[t];
    const float b2s = bb2[t];
    if (t < 128) b3p = ((const float2*)bb3)[t];
    if (t < 64)  b4p = ((const float2*)bb4)[t];
    float xs0 = 0.f, xs1 = 0.f, xa0 = 0.f, xa1 = 0.f;
    if (t < 64) {
        float2 xv = ((const float2*)x0)[row * 64 + t];
        xs0 = xv.x; xs1 = xv.y; xa0 = xs0; xa1 = xs1;
        vq[t] = packh(xs0, xs1);
    }
    __syncthreads();

    const float dt = 1.0f / (float)ODE_NSTEP;
    const uint4* vq4  = (const uint4*)vq;
    const uint4* h1q4 = (const uint4*)h1q;
    const uint4* h2q4 = (const uint4*)h2h;
    const uint4* h3q4 = (const uint4*)h3q;
    const uint4* g3q = (const uint4*)gW3;

    for (int it = 0; it < ODE_NSTEP * 4; ++it) {
        const int s = it & 3;
        // ---- L1: v(64kp) -> h1(256c). jA=col, khA=32kp slice. ----
        {
            float a0 = 0.f, a1 = 0.f, a2 = 0.f, a3 = 0.f;
#pragma unroll
            for (int m = 0; m < 8; ++m) {
                uint4 hv = vq4[khA * 8 + m];   // wave-uniform broadcast
                const int kp = khA * 32 + 4 * m;
                a0 = fdot2u(hv.x, gW1[(kp + 0) * 256 + jA], a0);
                a1 = fdot2u(hv.y, gW1[(kp + 1) * 256 + jA], a1);
                a2 = fdot2u(hv.z, gW1[(kp + 2) * 256 + jA], a2);
                a3 = fdot2u(hv.w, gW1[(kp + 3) * 256 + jA], a3);
            }
            part[khA * 256 + jA] = (a0 + a1) + (a2 + a3);
        }
        __syncthreads();
        if (t < 128) {
            const float2* p2 = (const float2*)part;
            float2 u0 = p2[t], u1 = p2[128 + t];
            h1q[t] = packh(fast_tanh(u0.x + u1.x + b1p.x), fast_tanh(u0.y + u1.y + b1p.y));
        }
        __syncthreads();
        // ---- L2: h1(128kp) -> h2(512c). Thread t = col t, full K. ----
        {
            float a0 = b2s, a1 = 0.f, a2 = 0.f, a3 = 0.f;
#pragma unroll
            for (int j = 0; j < 32; ++j) {
                uint4 hb = h1q4[j];  // wave-uniform broadcast
                a0 = fdot2u(hb.x, gW2[(4 * j + 0) * 512 + t], a0);
                a1 = fdot2u(hb.y, gW2[(4 * j + 1) * 512 + t], a1);
                a2 = fdot2u(hb.z, gW2[(4 * j + 2) * 512 + t], a2);
                a3 = fdot2u(hb.w, gW2[(4 * j + 3) * 512 + t], a3);
            }
            h2h[t] = f2h(fast_tanh((a0 + a1) + (a2 + a3)));
        }
        __syncthreads();
        // ---- L3: h2(256kp) -> h3(256c). kq16=16kp slice, g32=8 cols. ----
        {
            uint4 ha0 = h2q4[kq16 * 4], ha1 = h2q4[kq16 * 4 + 1];
            uint4 ha2 = h2q4[kq16 * 4 + 2], ha3 = h2q4[kq16 * 4 + 3];
            unsigned int hp[16] = {ha0.x, ha0.y, ha0.z, ha0.w, ha1.x, ha1.y, ha1.z, ha1.w,
                                   ha2.x, ha2.y, ha2.z, ha2.w, ha3.x, ha3.y, ha3.z, ha3.w};
            float a0 = 0.f, a1 = 0.f, a2 = 0.f, a3 = 0.f;
            float a4 = 0.f, a5 = 0.f, a6 = 0.f, a7 = 0.f;
#pragma unroll
            for (int i = 0; i < 16; ++i) {
                uint4 wv0 = g3q[(kq16 * 16 + i) * 64 + 2 * g32];
                uint4 wv1 = g3q[(kq16 * 16 + i) * 64 + 2 * g32 + 1];
                a0 = fdot2u(hp[i], wv0.x, a0); a1 = fdot2u(hp[i], wv0.y, a1);
                a2 = fdot2u(hp[i], wv0.z, a2); a3 = fdot2u(hp[i], wv0.w, a3);
                a4 = fdot2u(hp[i], wv1.x, a4); a5 = fdot2u(hp[i], wv1.y, a5);
                a6 = fdot2u(hp[i], wv1.z, a6); a7 = fdot2u(hp[i], wv1.w, a7);
            }
            *(f32x4*)(part + kq16 * 256 + 8 * g32)     = (f32x4){a0, a1, a2, a3};
            *(f32x4*)(part + kq16 * 256 + 8 * g32 + 4) = (f32x4){a4, a5, a6, a7};
        }
        __syncthreads();
        if (t < 128) {
            const float2* p2 = (const float2*)part;
            float z0 = b3p.x, z1 = b3p.y;
#pragma unroll
            for (int q = 0; q < 16; ++q) { float2 pv = p2[q * 128 + t]; z0 += pv.x; z1 += pv.y; }
            h3q[t] = packh(fast_tanh(z0), fast_tanh(z1));
        }
        __syncthreads();
        // ---- L4: h3(128kp) -> k(128c). jD=col, kqD=32kp slice. ----
        {
            float a0 = 0.f, a1 = 0.f, a2 = 0.f, a3 = 0.f;
#pragma unroll
            for (int m = 0; m < 8; ++m) {
                uint4 hv = h3q4[kqD * 8 + m];  // wave-uniform broadcast
                const int kp = kqD * 32 + 4 * m;
                a0 = fdot2u(hv.x, gW4[(kp + 0) * 128 + jD], a0);
                a1 = fdot2u(hv.y, gW4[(kp + 1) * 128 + jD], a1);
                a2 = fdot2u(hv.z, gW4[(kp + 2) * 128 + jD], a2);
                a3 = fdot2u(hv.w, gW4[(kp + 3) * 128 + jD], a3);
            }
            part[kqD * 128 + jD] = (a0 + a1) + (a2 + a3);
        }
        __syncthreads();
        if (t < 64) {
            const float2* p2 = (const float2*)part;
            float k0 = b4p.x, k1 = b4p.y;
#pragma unroll
            for (int q = 0; q < 4; ++q) { float2 pv = p2[q * 64 + t]; k0 += pv.x; k1 += pv.y; }
            float wB = (s == 0 || s == 3) ? dt * (1.f / 6.f) : dt * (1.f / 3.f);
            xa0 += wB * k0; xa1 += wB * k1;
            float v0, v1;
            if (s < 3) {
                float cc = (s == 2) ? dt : 0.5f * dt;
                v0 = xs0 + cc * k0; v1 = xs1 + cc * k1;
            } else {
                xs0 = xa0; xs1 = xa1; v0 = xs0; v1 = xs1;
            }
            vq[t] = packh(v0, v1);
        }
        __syncthreads();
    }
    if (t < 64) {
        float2 ov; ov.x = xs0; ov.y = xs1;
        ((float2*)branch)[row * 64 + t] = ov;
    }
}

// ---------------------------------------------------------------------------
// Trunk body, M=32 tile (4096 tiles): LDS 66.5KB -> 2 blocks/CU, 4 waves/SIMD.
// LDS: h1[32][512]swz @0 (32K) | h2 @32768 (32K) | coords @65536 | bw @66048
// ---------------------------------------------------------------------------
__device__ __forceinline__ int swz(int row, int byte_in_row) {
    return (row * 1024 + byte_in_row) ^ ((row & 15) << 4);
}

__device__ __forceinline__ void trunk_body(
    char* smem, int t2, bool serialTail,
    const float* __restrict__ coords,
    const float* __restrict__ tW1, const float* __restrict__ tb1,
    const unsigned short* __restrict__ tW2T, const float* __restrict__ tb2,
    const unsigned short* __restrict__ tW3T, const float* __restrict__ tb3,
    const float* __restrict__ oW, const float* __restrict__ ob,
    const float* __restrict__ branch, unsigned short* __restrict__ h3T,
    float* __restrict__ out) {
    const int t = threadIdx.x;
    const int b = t2 >> 6;              // 64 tiles per batch
    const int p0 = (t2 & 63) * 32;
    const int w = t >> 6, l = t & 63;
    const int lrow = l & 15, q = l >> 4, lk8 = q * 8;

    float* coordsLds = (float*)(smem + 65536);
    float* bwp = (float*)(smem + 66048);
    if (t < 128) coordsLds[t] = coords[(b * 2048 + p0) * 4 + t];
    else if (serialTail && t < 256) bwp[t - 128] = branch[b * 128 + (t - 128)] * oW[t - 128];
    __syncthreads();

    // ---- L1: h1[32][512] = relu(coords @ tW1 + tb1) -> bf16 swizzled @0 ----
    {
        const int r = t & 31, cs = t >> 5;   // row, 32-col group
        const float c0 = coordsLds[r * 4 + 0], c1 = coordsLds[r * 4 + 1];
        const float c2 = coordsLds[r * 4 + 2], c3 = coordsLds[r * 4 + 3];
#pragma unroll
        for (int i = 0; i < 32; i += 8) {
            const int c = cs * 32 + i;
            unsigned int pk[4];
#pragma unroll
            for (int u = 0; u < 4; ++u) {
                const int cu = c + 2 * u;
                float v0 = fmaxf(c0 * tW1[cu] + c1 * tW1[512 + cu] + c2 * tW1[1024 + cu] +
                                     c3 * tW1[1536 + cu] + tb1[cu], 0.f);
                float v1 = fmaxf(c0 * tW1[cu + 1] + c1 * tW1[512 + cu + 1] +
                                     c2 * tW1[1024 + cu + 1] + c3 * tW1[1536 + cu + 1] +
                                     tb1[cu + 1], 0.f);
                pk[u] = (unsigned int)f2bf(v0) | ((unsigned int)f2bf(v1) << 16);
            }
            uint4 pv; pv.x = pk[0]; pv.y = pk[1]; pv.z = pk[2]; pv.w = pk[3];
            *(uint4*)(smem + swz(r, c * 2)) = pv;
        }
    }
    __syncthreads();

    const unsigned short* bp2 = tW2T + (w * 4) * 8192 + q * 128 + lrow * 8;

    // ---- L2: h2[32][512]; swapped operands; wave w: 4 nt x 2 rt ----
    {
        f32x4 acc[4][2];
#pragma unroll
        for (int nt = 0; nt < 4; ++nt) {
            const int c0 = w * 64 + nt * 16 + q * 4;
            float4 bv = *(const float4*)(tb2 + c0);
#pragma unroll
            for (int rt = 0; rt < 2; ++rt) acc[nt][rt] = (f32x4){bv.x, bv.y, bv.z, bv.w};
        }
#pragma unroll
        for (int ksI = 0; ksI < 16; ++ksI) {
            const int kb = ksI * 32 + lk8;
            bf16x8 wf[4];
#pragma unroll
            for (int nt = 0; nt < 4; ++nt)
                wf[nt] = *(const bf16x8*)(bp2 + nt * 8192 + ksI * 512);
            bf16x8 hf[2];
#pragma unroll
            for (int rt = 0; rt < 2; ++rt)
                hf[rt] = *(const bf16x8*)(smem + swz(rt * 16 + lrow, kb * 2));
#pragma unroll
            for (int nt = 0; nt < 4; ++nt)
#pragma unroll
                for (int rt = 0; rt < 2; ++rt)
                    acc[nt][rt] = __builtin_amdgcn_mfma_f32_16x16x32_bf16(wf[nt], hf[rt], acc[nt][rt], 0, 0, 0);
        }
#pragma unroll
        for (int nt = 0; nt < 4; ++nt) {
            const int c0 = w * 64 + nt * 16 + q * 4;
#pragma unroll
            for (int rt = 0; rt < 2; ++rt) {
                float v0 = fmaxf(acc[nt][rt][0], 0.f);
                float v1 = fmaxf(acc[nt][rt][1], 0.f);
                float v2 = fmaxf(acc[nt][rt][2], 0.f);
                float v3 = fmaxf(acc[nt][rt][3], 0.f);
                uint2 pk;
                pk.x = (unsigned int)f2bf(v0) | ((unsigned int)f2bf(v1) << 16);
                pk.y = (unsigned int)f2bf(v2) | ((unsigned int)f2bf(v3) << 16);
                *(uint2*)(smem + 32768 + swz(rt * 16 + lrow, c0 * 2)) = pk;
            }
        }
    }
    __syncthreads();

    // ---- L3 (operand-swapped): wave = 2 d-tiles x 1 row-tile ----
    const int ct0 = (w & 3) * 2, rh = w >> 2;   // rh in {0,1}: rows rh*16..+15
    const unsigned short* bp3a = tW3T + (ct0 + 0) * 8192 + q * 128 + lrow * 8;
    const unsigned short* bp3b = tW3T + (ct0 + 1) * 8192 + q * 128 + lrow * 8;
    {
        const int dA = ct0 * 16 + q * 4, dB = dA + 16;
        float4 bva = *(const float4*)(tb3 + dA);
        float4 bvb = *(const float4*)(tb3 + dB);
        f32x4 accA = (f32x4){bva.x, bva.y, bva.z, bva.w};
        f32x4 accB = (f32x4){bvb.x, bvb.y, bvb.z, bvb.w};
#pragma unroll
        for (int ksI = 0; ksI < 16; ++ksI) {
            const int kb = ksI * 32 + lk8;
            bf16x8 bfa = *(const bf16x8*)(bp3a + ksI * 512);
            bf16x8 bfb = *(const bf16x8*)(bp3b + ksI * 512);
            bf16x8 af = *(const bf16x8*)(smem + 32768 + swz(rh * 16 + lrow, kb * 2));
            accA = __builtin_amdgcn_mfma_f32_16x16x32_bf16(bfa, af, accA, 0, 0, 0);
            accB = __builtin_amdgcn_mfma_f32_16x16x32_bf16(bfb, af, accB, 0, 0, 0);
        }
        if (!serialTail) {
            const int prow = p0 + rh * 16 + lrow;
            unsigned short* hrow = h3T + (unsigned long long)(b * 2048 + prow) * 128;
            {
                float v0 = fmaxf(accA[0], 0.f), v1 = fmaxf(accA[1], 0.f);
                float v2 = fmaxf(accA[2], 0.f), v3 = fmaxf(accA[3], 0.f);
                uint2 pk;
                pk.x = (unsigned int)f2bf(v0) | ((unsigned int)f2bf(v1) << 16);
                pk.y = (unsigned int)f2bf(v2) | ((unsigned int)f2bf(v3) << 16);
                *(uint2*)(hrow + dA) = pk;
            }
            {
                float v0 = fmaxf(accB[0], 0.f), v1 = fmaxf(accB[1], 0.f);
                float v2 = fmaxf(accB[2], 0.f), v3 = fmaxf(accB[3], 0.f);
                uint2 pk;
                pk.x = (unsigned int)f2bf(v0) | ((unsigned int)f2bf(v1) << 16);
                pk.y = (unsigned int)f2bf(v2) | ((unsigned int)f2bf(v3) << 16);
                *(uint2*)(hrow + dB) = pk;
            }
        } else {
            float* h3p = (float*)smem;  // h1 region dead
            const int rw = rh * 16 + lrow;
#pragma unroll
            for (int i = 0; i < 4; ++i) {
                h3p[rw * 132 + dA + i] = fmaxf(accA[i], 0.f);
                h3p[rw * 132 + dB + i] = fmaxf(accB[i], 0.f);
            }
            __syncthreads();
            const int p = t >> 4, seg = t & 15;
            float s = 0.f;
#pragma unroll
            for (int i = 0; i < 8; ++i) s += h3p[p * 132 + seg * 8 + i] * bwp[seg * 8 + i];
            s += __shfl_down(s, 8, 16);
            s += __shfl_down(s, 4, 16);
            s += __shfl_down(s, 2, 16);
            s += __shfl_down(s, 1, 16);
            if (seg == 0) out[b * 2048 + p0 + p] = s + ob[0];
        }
    }
}

// ---------------------------------------------------------------------------
extern __shared__ char mega_smem[];

__global__ __launch_bounds__(512, 4) void mega_kernel(
    int trunkOff, int serialTail,
    const float* __restrict__ x0, const float* __restrict__ coords,
    const unsigned int* __restrict__ gW1, const float* __restrict__ bb1,
    const unsigned int* __restrict__ gW2, const float* __restrict__ bb2,
    const unsigned int* __restrict__ gW3, const float* __restrict__ bb3,
    const unsigned int* __restrict__ gW4, const float* __restrict__ bb4,
    const float* __restrict__ tW1, const float* __restrict__ tb1,
    const unsigned short* __restrict__ tW2T, const float* __restrict__ tb2,
    const unsigned short* __restrict__ tW3T, const float* __restrict__ tb3,
    const float* __restrict__ oW, const float* __restrict__ ob,
    float* __restrict__ branch, unsigned short* __restrict__ h3T,
    float* __restrict__ out) {
    if ((int)blockIdx.x < trunkOff) {
        ode_body(mega_smem, blockIdx.x, x0, gW1, bb1, gW2, bb2, gW3, bb3, gW4, bb4, branch);
    } else {
        trunk_body(mega_smem, blockIdx.x - trunkOff, serialTail != 0,
                   coords, tW1, tb1, tW2T, tb2, tW3T, tb3, oW, ob, branch, h3T, out);
    }
}

// ---------------------------------------------------------------------------
// Combine: h3T p-major -> 16 contiguous b128 loads per output element.
// ---------------------------------------------------------------------------
__global__ __launch_bounds__(512) void combine_kernel(
    const float* __restrict__ branch, const float* __restrict__ oW,
    const float* __restrict__ ob, const unsigned short* __restrict__ h3T,
    float* __restrict__ out) {
    __shared__ float u[128];
    const int t = threadIdx.x;
    const int b = blockIdx.x >> 2;
    const int p = ((blockIdx.x & 3) << 9) + t;
    if (t < 128) u[t] = branch[b * 128 + t] * oW[t];
    __syncthreads();
    const uint4* hp = (const uint4*)(h3T + (unsigned long long)(b * 2048 + p) * 128);
    float acc = ob[0];
#pragma unroll
    for (int i = 0; i < 16; ++i) {
        uint4 v = hp[i];
        const float* uu = u + i * 8;
        acc += bf2f(v.x & 0xffffu) * uu[0] + bf2f(v.x >> 16) * uu[1] +
               bf2f(v.y & 0xffffu) * uu[2] + bf2f(v.y >> 16) * uu[3] +
               bf2f(v.z & 0xffffu) * uu[4] + bf2f(v.z >> 16) * uu[5] +
               bf2f(v.w & 0xffffu) * uu[6] + bf2f(v.w >> 16) * uu[7];
    }
    out[b * 2048 + p] = acc;
}

// ---------------------------------------------------------------------------
extern "C" void kernel_launch(void* const* d_in, const int* in_sizes, int n_in,
                              void* d_out, int out_size, void* d_ws, size_t ws_size,
                              hipStream_t stream) {
    const float* parameter = (const float*)d_in[0];
    const float* coords    = (const float*)d_in[1];
    const float* bW1 = (const float*)d_in[2];  const float* bb1 = (const float*)d_in[3];
    const float* bW2 = (const float*)d_in[4];  const float* bb2 = (const float*)d_in[5];
    const float* bW3 = (const float*)d_in[6];  const float* bb3 = (const float*)d_in[7];
    const float* bW4 = (const float*)d_in[8];  const float* bb4 = (const float*)d_in[9];
    const float* tW1 = (const float*)d_in[10]; const float* tb1 = (const float*)d_in[11];
    const float* tW2 = (const float*)d_in[12]; const float* tb2 = (const float*)d_in[13];
    const float* tW3 = (const float*)d_in[14]; const float* tb3 = (const float*)d_in[15];
    const float* oW  = (const float*)d_in[16]; const float* ob  = (const float*)d_in[17];

    char* ws = (char*)d_ws;
    unsigned short* tW2T = (unsigned short*)(ws);             // 524288
    unsigned short* tW3T = (unsigned short*)(ws + 524288);    // 131072
    unsigned int*   W1u  = (unsigned int*)(ws + 655360);      // 65536
    unsigned int*   W2u  = (unsigned int*)(ws + 720896);      // 262144
    unsigned int*   W3u  = (unsigned int*)(ws + 983040);      // 262144
    unsigned int*   W4u  = (unsigned int*)(ws + 1245184);     // 65536
    float* branch        = (float*)(ws + 1310720);            // 32768
    unsigned short* h3T  = (unsigned short*)(ws + 2097152);   // 33554432
    float* out = (float*)d_out;

    const bool fused = (ws_size >= 35651584ull);

    hipLaunchKernelGGL(convert_kernel, dim3(1920), dim3(256), 0, stream,
                       tW2, tW3, bW1, bW2, bW3, bW4,
                       tW2T, tW3T, W1u, W2u, W3u, W4u);

    hipFuncSetAttribute(reinterpret_cast<const void*>(&mega_kernel),
                        hipFuncAttributeMaxDynamicSharedMemorySize, 66560);

    if (fused) {
        hipLaunchKernelGGL(mega_kernel, dim3(64 + 4096), dim3(512), 66560, stream,
                           64, 0, parameter, coords, W1u, bb1, W2u, bb2, W3u, bb3, W4u, bb4,
                           tW1, tb1, tW2T, tb2, tW3T, tb3, oW, ob, branch, h3T, out);
        hipLaunchKernelGGL(combine_kernel, dim3(256), dim3(512), 0, stream,
                           branch, oW, ob, h3T, out);
    } else {
        hipLaunchKernelGGL(mega_kernel, dim3(64), dim3(512), 66560, stream,
                           64, 1, parameter, coords, W1u, bb1, W2u, bb2, W3u, bb3, W4u, bb4,
                           tW1, tb1, tW2T, tb2, tW3T, tb3, oW, ob, branch, h3T, out);
        hipLaunchKernelGGL(mega_kernel, dim3(4096), dim3(512), 66560, stream,
                           0, 1, parameter, coords, W1u, bb1, W2u, bb2, W3u, bb3, W4u, bb4,
                           tW1, tb1, tW2T, tb2, tW3T, tb3, oW, ob, branch, h3T, out);
    }
}

// Round 21
// 140.924 us; speedup vs baseline: 1.7620x; 1.7620x over previous
//
#include <hip/hip_runtime.h>
#include <hip/hip_bf16.h>

using bf16x8 = __attribute__((ext_vector_type(8))) short;
using f32x4  = __attribute__((ext_vector_type(4))) float;
using f16x2  = __attribute__((ext_vector_type(2))) _Float16;

#define ODE_NSTEP 1  // RK4 single step; bit-identical absmax through nine step halvings (r9-r19)

__device__ __forceinline__ unsigned short f2bf(float f) {
    unsigned int u = __float_as_uint(f);
    return (unsigned short)((u + 0x7fffu + ((u >> 16) & 1u)) >> 16);
}
__device__ __forceinline__ float bf2f(unsigned int s) {
    return __uint_as_float(s << 16);
}
__device__ __forceinline__ unsigned short f2h(float f) {
    _Float16 h = (_Float16)f;
    return __builtin_bit_cast(unsigned short, h);
}
__device__ __forceinline__ unsigned int packh(float lo, float hi) {
    return (unsigned int)f2h(lo) | ((unsigned int)f2h(hi) << 16);
}
__device__ __forceinline__ float fdot2u(unsigned int a, unsigned int b, float c) {
#if __has_builtin(__builtin_amdgcn_fdot2)
    return __builtin_amdgcn_fdot2(__builtin_bit_cast(f16x2, a),
                                  __builtin_bit_cast(f16x2, b), c, false);
#else
    f16x2 av = __builtin_bit_cast(f16x2, a), bv = __builtin_bit_cast(f16x2, b);
    return c + (float)av.x * (float)bv.x + (float)av.y * (float)bv.y;
#endif
}
__device__ __forceinline__ float fast_tanh(float xx) {
    float a = __expf(-2.f * fabsf(xx));
    float r = (1.f - a) / (1.f + a);
    return copysignf(r, xx);
}

// ---------------------------------------------------------------------------
// K0: weight repack (trunk B tiled [col/16][k/8][16][8]).
// ---------------------------------------------------------------------------
__global__ void convert_kernel(const float* __restrict__ tW2, const float* __restrict__ tW3,
                               const float* __restrict__ bW1, const float* __restrict__ bW2,
                               const float* __restrict__ bW3, const float* __restrict__ bW4,
                               unsigned short* __restrict__ tW2T, unsigned short* __restrict__ tW3T,
                               unsigned int* __restrict__ W1u, unsigned int* __restrict__ W2u,
                               unsigned int* __restrict__ W3u, unsigned int* __restrict__ W4u) {
    int idx = blockIdx.x * blockDim.x + threadIdx.x;
    if (idx < 262144) {
        int cb = idx >> 13, rem = idx & 8191;
        int kb = rem >> 7, rem2 = rem & 127;
        int cl = rem2 >> 3, kl = rem2 & 7;
        int col = cb * 16 + cl, k = kb * 8 + kl;
        tW2T[idx] = f2bf(tW2[k * 512 + col]);
    } else if (idx < 327680) {
        int i = idx - 262144;
        int cb = i >> 13, rem = i & 8191;
        int kb = rem >> 7, rem2 = rem & 127;
        int cl = rem2 >> 3, kl = rem2 & 7;
        int col = cb * 16 + cl, k = kb * 8 + kl;
        tW3T[i] = f2bf(tW3[k * 128 + col]);
    } else if (idx < 344064) {
        int i = idx - 327680, kp = i >> 8, c = i & 255;
        W1u[i] = packh(bW1[(2 * kp) * 256 + c], bW1[(2 * kp + 1) * 256 + c]);
    } else if (idx < 409600) {
        int i = idx - 344064, kp = i >> 9, c = i & 511;
        W2u[i] = packh(bW2[(2 * kp) * 512 + c], bW2[(2 * kp + 1) * 512 + c]);
    } else if (idx < 475136) {
        int i = idx - 409600, kp = i >> 8, c = i & 255;
        W3u[i] = packh(bW3[(2 * kp) * 256 + c], bW3[(2 * kp + 1) * 256 + c]);
    } else if (idx < 491520) {
        int i = idx - 475136, kp = i >> 7, c = i & 127;
        W4u[i] = packh(bW4[(2 * kp) * 128 + c], bW4[(2 * kp + 1) * 128 + c]);
    }
}

// ---------------------------------------------------------------------------
// ODE body (r19 configuration; W2 in AGPRs, verified r7-r19).
// ---------------------------------------------------------------------------
__device__ __forceinline__ void ode_body(
    char* smem, int row,
    const float* __restrict__ x0,
    const unsigned int* __restrict__ gW1, const float* __restrict__ bb1,
    const unsigned int* __restrict__ gW2, const float* __restrict__ bb2,
    const unsigned int* __restrict__ gW3, const float* __restrict__ bb3,
    const unsigned int* __restrict__ gW4, const float* __restrict__ bb4,
    float* __restrict__ branch) {
    unsigned int* w1  = (unsigned int*)smem;
    unsigned int* w4  = (unsigned int*)(smem + 65536);
    float*        part = (float*)(smem + 131072);
    unsigned int* vq  = (unsigned int*)(smem + 147456);
    unsigned int* h1q = (unsigned int*)(smem + 147712);
    unsigned short* h2h = (unsigned short*)(smem + 148224);
    unsigned int* h3q = (unsigned int*)(smem + 149248);

    const int t = threadIdx.x;
    const int lane = t & 63, wave = t >> 6;
    const int kq16 = t >> 5, g32 = t & 31;

    {   // stage resident weights
        const uint4* s1 = (const uint4*)gW1; uint4* d1 = (uint4*)w1;
#pragma unroll
        for (int i = 0; i < 8; ++i) d1[t + i * 512] = s1[t + i * 512];
        const uint4* s4 = (const uint4*)gW4; uint4* d4 = (uint4*)w4;
#pragma unroll
        for (int i = 0; i < 8; ++i) d4[t + i * 512] = s4[t + i * 512];
    }
    // W2 -> AGPRs. Thread t owns output col t: 128 f16-pairs (= full K=256).
    unsigned int w2a[128];
#pragma unroll
    for (int j = 0; j < 128; ++j) {
        unsigned int v = gW2[j * 512 + t];
        asm volatile("v_accvgpr_write_b32 %0, %1" : "=a"(w2a[j]) : "v"(v));
    }

    float2 b1p = make_float2(0.f, 0.f), b3p = b1p, b4p = b1p;
    if (t < 128) b1p = ((const float2*)bb1)[t];
    const float b2s = bb2[t];
    if (t < 128) b3p = ((const float2*)bb3)[t];
    if (t < 64)  b4p = ((const float2*)bb4)[t];
    float xs0 = 0.f, xs1 = 0.f, xa0 = 0.f, xa1 = 0.f;
    if (t < 64) {
        float2 xv = ((const float2*)x0)[row * 64 + t];
        xs0 = xv.x; xs1 = xv.y; xa0 = xs0; xa1 = xs1;
        vq[t] = packh(xs0, xs1);
    }
    __syncthreads();

    const float dt = 1.0f / (float)ODE_NSTEP;
    const uint4* vq4  = (const uint4*)vq;
    const uint4* h1q4 = (const uint4*)h1q;
    const uint4* h2q4 = (const uint4*)h2h;
    const uint4* h3q4 = (const uint4*)h3q;
    const uint4* w1q = (const uint4*)w1;
    const uint4* w4q = (const uint4*)w4;
    const uint4* g3q = (const uint4*)gW3;

    for (int it = 0; it < ODE_NSTEP * 4; ++it) {
        const int s = it & 3;
        // ---- L1: v(64kp) -> h1(256c). W1 LDS. wave=8kp slice, lane=4 cols ----
        {
            uint4 va = vq4[wave * 2], vb = vq4[wave * 2 + 1];
            unsigned int hp[8] = {va.x, va.y, va.z, va.w, vb.x, vb.y, vb.z, vb.w};
            float a0 = 0.f, a1 = 0.f, a2 = 0.f, a3 = 0.f;
#pragma unroll
            for (int j = 0; j < 8; ++j) {
                uint4 wv = w1q[(wave * 8 + j) * 64 + lane];
                a0 = fdot2u(hp[j], wv.x, a0); a1 = fdot2u(hp[j], wv.y, a1);
                a2 = fdot2u(hp[j], wv.z, a2); a3 = fdot2u(hp[j], wv.w, a3);
            }
            *(f32x4*)(part + wave * 256 + 4 * lane) = (f32x4){a0, a1, a2, a3};
        }
        __syncthreads();
        if (t < 128) {
            const float2* p2 = (const float2*)part;
            float z0 = b1p.x, z1 = b1p.y;
#pragma unroll
            for (int q = 0; q < 8; ++q) { float2 pv = p2[q * 128 + t]; z0 += pv.x; z1 += pv.y; }
            h1q[t] = packh(fast_tanh(z0), fast_tanh(z1));
        }
        __syncthreads();
        // prefetch W3 (iters 0..3): retires under the L2 VALU phase below.
        uint4 w3p0 = g3q[(kq16 * 16 + 0) * 64 + 2 * g32];
        uint4 w3p1 = g3q[(kq16 * 16 + 0) * 64 + 2 * g32 + 1];
        uint4 w3p2 = g3q[(kq16 * 16 + 1) * 64 + 2 * g32];
        uint4 w3p3 = g3q[(kq16 * 16 + 1) * 64 + 2 * g32 + 1];
        uint4 w3p4 = g3q[(kq16 * 16 + 2) * 64 + 2 * g32];
        uint4 w3p5 = g3q[(kq16 * 16 + 2) * 64 + 2 * g32 + 1];
        uint4 w3p6 = g3q[(kq16 * 16 + 3) * 64 + 2 * g32];
        uint4 w3p7 = g3q[(kq16 * 16 + 3) * 64 + 2 * g32 + 1];
        // ---- L2: h1(128kp) -> h2(512c). W2 from AGPRs, full-K per thread ----
        {
            float a0 = b2s, a1 = 0.f, a2 = 0.f, a3 = 0.f;
#pragma unroll
            for (int j = 0; j < 32; ++j) {
                uint4 hb = h1q4[j];  // wave-uniform broadcast
                unsigned int wx, wy, wz, ww;
                asm volatile("v_accvgpr_read_b32 %0, %1" : "=v"(wx) : "a"(w2a[4 * j + 0]));
                asm volatile("v_accvgpr_read_b32 %0, %1" : "=v"(wy) : "a"(w2a[4 * j + 1]));
                asm volatile("v_accvgpr_read_b32 %0, %1" : "=v"(wz) : "a"(w2a[4 * j + 2]));
                asm volatile("v_accvgpr_read_b32 %0, %1" : "=v"(ww) : "a"(w2a[4 * j + 3]));
                a0 = fdot2u(hb.x, wx, a0); a1 = fdot2u(hb.y, wy, a1);
                a2 = fdot2u(hb.z, wz, a2); a3 = fdot2u(hb.w, ww, a3);
            }
            h2h[t] = f2h(fast_tanh((a0 + a1) + (a2 + a3)));
        }
        __syncthreads();
        // ---- L3: h2(256kp) -> h3(256c). streamed. kq16=16kp slice, g32=8 cols ----
        {
            uint4 ha0 = h2q4[kq16 * 4], ha1 = h2q4[kq16 * 4 + 1];
            uint4 ha2 = h2q4[kq16 * 4 + 2], ha3 = h2q4[kq16 * 4 + 3];
            unsigned int hp[16] = {ha0.x, ha0.y, ha0.z, ha0.w, ha1.x, ha1.y, ha1.z, ha1.w,
                                   ha2.x, ha2.y, ha2.z, ha2.w, ha3.x, ha3.y, ha3.z, ha3.w};
            float a0 = 0.f, a1 = 0.f, a2 = 0.f, a3 = 0.f;
            float a4 = 0.f, a5 = 0.f, a6 = 0.f, a7 = 0.f;
#pragma unroll
            for (int i = 0; i < 16; ++i) {
                uint4 wv0, wv1;
                if (i == 0)      { wv0 = w3p0; wv1 = w3p1; }
                else if (i == 1) { wv0 = w3p2; wv1 = w3p3; }
                else if (i == 2) { wv0 = w3p4; wv1 = w3p5; }
                else if (i == 3) { wv0 = w3p6; wv1 = w3p7; }
                else {
                    wv0 = g3q[(kq16 * 16 + i) * 64 + 2 * g32];
                    wv1 = g3q[(kq16 * 16 + i) * 64 + 2 * g32 + 1];
                }
                a0 = fdot2u(hp[i], wv0.x, a0); a1 = fdot2u(hp[i], wv0.y, a1);
                a2 = fdot2u(hp[i], wv0.z, a2); a3 = fdot2u(hp[i], wv0.w, a3);
                a4 = fdot2u(hp[i], wv1.x, a4); a5 = fdot2u(hp[i], wv1.y, a5);
                a6 = fdot2u(hp[i], wv1.z, a6); a7 = fdot2u(hp[i], wv1.w, a7);
            }
            *(f32x4*)(part + kq16 * 256 + 8 * g32)     = (f32x4){a0, a1, a2, a3};
            *(f32x4*)(part + kq16 * 256 + 8 * g32 + 4) = (f32x4){a4, a5, a6, a7};
        }
        __syncthreads();
        if (t < 128) {
            const float2* p2 = (const float2*)part;
            float z0 = b3p.x, z1 = b3p.y;
#pragma unroll
            for (int q = 0; q < 16; ++q) { float2 pv = p2[q * 128 + t]; z0 += pv.x; z1 += pv.y; }
            h3q[t] = packh(fast_tanh(z0), fast_tanh(z1));
        }
        __syncthreads();
        // ---- L4: h3(128kp) -> k(128c). W4 LDS. kq16=8kp slice, g32=4 cols ----
        {
            uint4 ha0 = h3q4[kq16 * 2], ha1 = h3q4[kq16 * 2 + 1];
            unsigned int hp[8] = {ha0.x, ha0.y, ha0.z, ha0.w, ha1.x, ha1.y, ha1.z, ha1.w};
            float a0 = 0.f, a1 = 0.f, a2 = 0.f, a3 = 0.f;
#pragma unroll
            for (int i = 0; i < 8; ++i) {
                uint4 wv = w4q[(kq16 * 8 + i) * 32 + g32];
                a0 = fdot2u(hp[i], wv.x, a0); a1 = fdot2u(hp[i], wv.y, a1);
                a2 = fdot2u(hp[i], wv.z, a2); a3 = fdot2u(hp[i], wv.w, a3);
            }
            *(f32x4*)(part + kq16 * 128 + 4 * g32) = (f32x4){a0, a1, a2, a3};
        }
        __syncthreads();
        if (t < 64) {
            const float2* p2 = (const float2*)part;
            float k0 = b4p.x, k1 = b4p.y;
#pragma unroll
            for (int q = 0; q < 16; ++q) { float2 pv = p2[q * 64 + t]; k0 += pv.x; k1 += pv.y; }
            float wB = (s == 0 || s == 3) ? dt * (1.f / 6.f) : dt * (1.f / 3.f);
            xa0 += wB * k0; xa1 += wB * k1;
            float v0, v1;
            if (s < 3) {
                float cc = (s == 2) ? dt : 0.5f * dt;
                v0 = xs0 + cc * k0; v1 = xs1 + cc * k1;
            } else {
                xs0 = xa0; xs1 = xa1; v0 = xs0; v1 = xs1;
            }
            vq[t] = packh(v0, v1);
        }
        __syncthreads();
    }
    if (t < 64) {
        float2 ov; ov.x = xs0; ov.y = xs1;
        ((float2*)branch)[row * 64 + t] = ov;
    }
}

// ---------------------------------------------------------------------------
// Trunk body (r19 configuration, M=64).
// ---------------------------------------------------------------------------
__device__ __forceinline__ int swz(int row, int byte_in_row) {
    return (row * 1024 + byte_in_row) ^ ((row & 15) << 4);
}

__device__ __forceinline__ void trunk_body(
    char* smem, int t2, bool serialTail,
    const float* __restrict__ coords,
    const float* __restrict__ tW1, const float* __restrict__ tb1,
    const unsigned short* __restrict__ tW2T, const float* __restrict__ tb2,
    const unsigned short* __restrict__ tW3T, const float* __restrict__ tb3,
    const float* __restrict__ oW, const float* __restrict__ ob,
    const float* __restrict__ branch, unsigned short* __restrict__ h3T,
    float* __restrict__ out) {
    const int t = threadIdx.x;
    const int b = t2 >> 5;
    const int p0 = (t2 & 31) * 64;
    const int w = t >> 6, l = t & 63;
    const int lrow = l & 15, q = l >> 4, lk8 = q * 8;

    const unsigned short* bp2 = tW2T + (w * 4) * 8192 + q * 128 + lrow * 8;

    // Early-issue W2 fragments for ksI=0,1: retire under coords-load + L1.
    bf16x8 wf0[4], wf1[4];
#pragma unroll
    for (int nt = 0; nt < 4; ++nt) {
        wf0[nt] = *(const bf16x8*)(bp2 + nt * 8192);
        wf1[nt] = *(const bf16x8*)(bp2 + nt * 8192 + 512);
    }

    float* coordsLds = (float*)(smem + 131072);
    float* bwp = (float*)(smem + 132096);
    if (t < 256) coordsLds[t] = coords[(b * 2048 + p0) * 4 + t];
    else if (serialTail && t < 384) bwp[t - 256] = branch[b * 128 + (t - 256)] * oW[t - 256];
    __syncthreads();

    // ---- L1: h1[64][512] = relu(coords @ tW1 + tb1) -> bf16 swizzled @0 ----
    {
        const int r = t & 63;
        const int cs = __builtin_amdgcn_readfirstlane(t >> 6);  // uniform -> s_loads
        const float c0 = coordsLds[r * 4 + 0], c1 = coordsLds[r * 4 + 1];
        const float c2 = coordsLds[r * 4 + 2], c3 = coordsLds[r * 4 + 3];
#pragma unroll
        for (int i = 0; i < 64; i += 8) {
            const int c = cs * 64 + i;
            unsigned int pk[4];
#pragma unroll
            for (int u = 0; u < 4; ++u) {
                const int cu = c + 2 * u;
                float v0 = fmaxf(c0 * tW1[cu] + c1 * tW1[512 + cu] + c2 * tW1[1024 + cu] +
                                     c3 * tW1[1536 + cu] + tb1[cu], 0.f);
                float v1 = fmaxf(c0 * tW1[cu + 1] + c1 * tW1[512 + cu + 1] +
                                     c2 * tW1[1024 + cu + 1] + c3 * tW1[1536 + cu + 1] +
                                     tb1[cu + 1], 0.f);
                pk[u] = (unsigned int)f2bf(v0) | ((unsigned int)f2bf(v1) << 16);
            }
            uint4 pv; pv.x = pk[0]; pv.y = pk[1]; pv.z = pk[2]; pv.w = pk[3];
            *(uint4*)(smem + swz(r, c * 2)) = pv;   // b128, conflict-free
        }
    }
    __syncthreads();

    // ---- L2: h2[64][512]; swapped operands, builtin MFMA, bias in acc init ----
    {
        f32x4 acc[4][4];  // [nt][rt]; reg i = col (w*64+nt*16+q*4+i), lane&15 = row
#pragma unroll
        for (int nt = 0; nt < 4; ++nt) {
            const int c0 = w * 64 + nt * 16 + q * 4;
            float4 bv = *(const float4*)(tb2 + c0);
#pragma unroll
            for (int rt = 0; rt < 4; ++rt) acc[nt][rt] = (f32x4){bv.x, bv.y, bv.z, bv.w};
        }
#pragma unroll
        for (int ksI = 0; ksI < 16; ++ksI) {
            const int kb = ksI * 32 + lk8;
            bf16x8 wf[4];
            if (ksI == 0) {
#pragma unroll
                for (int nt = 0; nt < 4; ++nt) wf[nt] = wf0[nt];
            } else if (ksI == 1) {
#pragma unroll
                for (int nt = 0; nt < 4; ++nt) wf[nt] = wf1[nt];
            } else {
#pragma unroll
                for (int nt = 0; nt < 4; ++nt)
                    wf[nt] = *(const bf16x8*)(bp2 + nt * 8192 + ksI * 512);
            }
            bf16x8 hf[4];
#pragma unroll
            for (int rt = 0; rt < 4; ++rt)
                hf[rt] = *(const bf16x8*)(smem + swz(rt * 16 + lrow, kb * 2));
#pragma unroll
            for (int nt = 0; nt < 4; ++nt)
#pragma unroll
                for (int rt = 0; rt < 4; ++rt)
                    acc[nt][rt] = __builtin_amdgcn_mfma_f32_16x16x32_bf16(wf[nt], hf[rt], acc[nt][rt], 0, 0, 0);
        }
#pragma unroll
        for (int nt = 0; nt < 4; ++nt) {
            const int c0 = w * 64 + nt * 16 + q * 4;
#pragma unroll
            for (int rt = 0; rt < 4; ++rt) {
                float v0 = fmaxf(acc[nt][rt][0], 0.f);
                float v1 = fmaxf(acc[nt][rt][1], 0.f);
                float v2 = fmaxf(acc[nt][rt][2], 0.f);
                float v3 = fmaxf(acc[nt][rt][3], 0.f);
                uint2 pk;
                pk.x = (unsigned int)f2bf(v0) | ((unsigned int)f2bf(v1) << 16);
                pk.y = (unsigned int)f2bf(v2) | ((unsigned int)f2bf(v3) << 16);
                *(uint2*)(smem + 65536 + swz(rt * 16 + lrow, c0 * 2)) = pk;
            }
        }
    }
    // L3 mapping: ct0 = (w&3)*2 (2 d-tiles), rh = w>>2 (p-rows rh*32..+31).
    const int ct0 = (w & 3) * 2, rh = w >> 2;
    const unsigned short* bp3a = tW3T + (ct0 + 0) * 8192 + q * 128 + lrow * 8;
    const unsigned short* bp3b = tW3T + (ct0 + 1) * 8192 + q * 128 + lrow * 8;
    // Early-issue W3 fragments for ksI=0: retire across the barrier.
    bf16x8 b3a0 = *(const bf16x8*)(bp3a);
    bf16x8 b3b0 = *(const bf16x8*)(bp3b);
    __syncthreads();

    // ---- L3 (operand-swapped): C lane&15 = p-in-tile, reg i = d quad ----
    {
        const int dA = ct0 * 16 + q * 4, dB = dA + 16;
        float4 bva = *(const float4*)(tb3 + dA);
        float4 bvb = *(const float4*)(tb3 + dB);
        f32x4 accA[2], accB[2];
#pragma unroll
        for (int r = 0; r < 2; ++r) {
            accA[r] = (f32x4){bva.x, bva.y, bva.z, bva.w};
            accB[r] = (f32x4){bvb.x, bvb.y, bvb.z, bvb.w};
        }
#pragma unroll
        for (int ksI = 0; ksI < 16; ++ksI) {
            const int kb = ksI * 32 + lk8;
            bf16x8 bfa = (ksI == 0) ? b3a0 : *(const bf16x8*)(bp3a + ksI * 512);
            bf16x8 bfb = (ksI == 0) ? b3b0 : *(const bf16x8*)(bp3b + ksI * 512);
            bf16x8 af[2];
#pragma unroll
            for (int r = 0; r < 2; ++r)
                af[r] = *(const bf16x8*)(smem + 65536 + swz((rh * 2 + r) * 16 + lrow, kb * 2));
#pragma unroll
            for (int r = 0; r < 2; ++r) {
                accA[r] = __builtin_amdgcn_mfma_f32_16x16x32_bf16(bfa, af[r], accA[r], 0, 0, 0);
                accB[r] = __builtin_amdgcn_mfma_f32_16x16x32_bf16(bfb, af[r], accB[r], 0, 0, 0);
            }
        }
        if (!serialTail) {
#pragma unroll
            for (int r = 0; r < 2; ++r) {
                const int prow = p0 + (rh * 2 + r) * 16 + lrow;
                unsigned short* hrow = h3T + (unsigned long long)(b * 2048 + prow) * 128;
                {
                    float v0 = fmaxf(accA[r][0], 0.f), v1 = fmaxf(accA[r][1], 0.f);
                    float v2 = fmaxf(accA[r][2], 0.f), v3 = fmaxf(accA[r][3], 0.f);
                    uint2 pk;
                    pk.x = (unsigned int)f2bf(v0) | ((unsigned int)f2bf(v1) << 16);
                    pk.y = (unsigned int)f2bf(v2) | ((unsigned int)f2bf(v3) << 16);
                    *(uint2*)(hrow + dA) = pk;
                }
                {
                    float v0 = fmaxf(accB[r][0], 0.f), v1 = fmaxf(accB[r][1], 0.f);
                    float v2 = fmaxf(accB[r][2], 0.f), v3 = fmaxf(accB[r][3], 0.f);
                    uint2 pk;
                    pk.x = (unsigned int)f2bf(v0) | ((unsigned int)f2bf(v1) << 16);
                    pk.y = (unsigned int)f2bf(v2) | ((unsigned int)f2bf(v3) << 16);
                    *(uint2*)(hrow + dB) = pk;
                }
            }
        } else {
            float* h3p = (float*)smem;
#pragma unroll
            for (int r = 0; r < 2; ++r)
#pragma unroll
                for (int i = 0; i < 4; ++i) {
                    int rw = (rh * 2 + r) * 16 + lrow;
                    h3p[rw * 132 + dA + i] = fmaxf(accA[r][i], 0.f);
                    h3p[rw * 132 + dB + i] = fmaxf(accB[r][i], 0.f);
                }
            __syncthreads();
            const int p = t >> 3, seg = t & 7;
            float s = 0.f;
#pragma unroll
            for (int i = 0; i < 16; ++i) s += h3p[p * 132 + seg * 16 + i] * bwp[seg * 16 + i];
            s += __shfl_down(s, 4, 8);
            s += __shfl_down(s, 2, 8);
            s += __shfl_down(s, 1, 8);
            if (seg == 0) out[b * 2048 + p0 + p] = s + ob[0];
        }
    }
}

// ---------------------------------------------------------------------------
extern __shared__ char mega_smem[];

__global__ __launch_bounds__(512, 2) void mega_kernel(
    int trunkOff, int serialTail,
    const float* __restrict__ x0, const float* __restrict__ coords,
    const unsigned int* __restrict__ gW1, const float* __restrict__ bb1,
    const unsigned int* __restrict__ gW2, const float* __restrict__ bb2,
    const unsigned int* __restrict__ gW3, const float* __restrict__ bb3,
    const unsigned int* __restrict__ gW4, const float* __restrict__ bb4,
    const float* __restrict__ tW1, const float* __restrict__ tb1,
    const unsigned short* __restrict__ tW2T, const float* __restrict__ tb2,
    const unsigned short* __restrict__ tW3T, const float* __restrict__ tb3,
    const float* __restrict__ oW, const float* __restrict__ ob,
    float* __restrict__ branch, unsigned short* __restrict__ h3T,
    float* __restrict__ out) {
    if ((int)blockIdx.x < trunkOff) {
        ode_body(mega_smem, blockIdx.x, x0, gW1, bb1, gW2, bb2, gW3, bb3, gW4, bb4, branch);
    } else {
        trunk_body(mega_smem, blockIdx.x - trunkOff, serialTail != 0,
                   coords, tW1, tb1, tW2T, tb2, tW3T, tb3, oW, ob, branch, h3T, out);
    }
}

// ---------------------------------------------------------------------------
// Combine: h3T is p-major -> 16 contiguous b128 loads per output element.
// ---------------------------------------------------------------------------
__global__ __launch_bounds__(512) void combine_kernel(
    const float* __restrict__ branch, const float* __restrict__ oW,
    const float* __restrict__ ob, const unsigned short* __restrict__ h3T,
    float* __restrict__ out) {
    __shared__ float u[128];
    const int t = threadIdx.x;
    const int b = blockIdx.x >> 2;
    const int p = ((blockIdx.x & 3) << 9) + t;
    if (t < 128) u[t] = branch[b * 128 + t] * oW[t];
    __syncthreads();
    const uint4* hp = (const uint4*)(h3T + (unsigned long long)(b * 2048 + p) * 128);
    float acc = ob[0];
#pragma unroll
    for (int i = 0; i < 16; ++i) {
        uint4 v = hp[i];
        const float* uu = u + i * 8;
        acc += bf2f(v.x & 0xffffu) * uu[0] + bf2f(v.x >> 16) * uu[1] +
               bf2f(v.y & 0xffffu) * uu[2] + bf2f(v.y >> 16) * uu[3] +
               bf2f(v.z & 0xffffu) * uu[4] + bf2f(v.z >> 16) * uu[5] +
               bf2f(v.w & 0xffffu) * uu[6] + bf2f(v.w >> 16) * uu[7];
    }
    out[b * 2048 + p] = acc;
}

// ---------------------------------------------------------------------------
extern "C" void kernel_launch(void* const* d_in, const int* in_sizes, int n_in,
                              void* d_out, int out_size, void* d_ws, size_t ws_size,
                              hipStream_t stream) {
    const float* parameter = (const float*)d_in[0];
    const float* coords    = (const float*)d_in[1];
    const float* bW1 = (const float*)d_in[2];  const float* bb1 = (const float*)d_in[3];
    const float* bW2 = (const float*)d_in[4];  const float* bb2 = (const float*)d_in[5];
    const float* bW3 = (const float*)d_in[6];  const float* bb3 = (const float*)d_in[7];
    const float* bW4 = (const float*)d_in[8];  const float* bb4 = (const float*)d_in[9];
    const float* tW1 = (const float*)d_in[10]; const float* tb1 = (const float*)d_in[11];
    const float* tW2 = (const float*)d_in[12]; const float* tb2 = (const float*)d_in[13];
    const float* tW3 = (const float*)d_in[14]; const float* tb3 = (const float*)d_in[15];
    const float* oW  = (const float*)d_in[16]; const float* ob  = (const float*)d_in[17];

    char* ws = (char*)d_ws;
    unsigned short* tW2T = (unsigned short*)(ws);             // 524288
    unsigned short* tW3T = (unsigned short*)(ws + 524288);    // 131072
    unsigned int*   W1u  = (unsigned int*)(ws + 655360);      // 65536
    unsigned int*   W2u  = (unsigned int*)(ws + 720896);      // 262144
    unsigned int*   W3u  = (unsigned int*)(ws + 983040);      // 262144
    unsigned int*   W4u  = (unsigned int*)(ws + 1245184);     // 65536
    float* branch        = (float*)(ws + 1310720);            // 32768
    unsigned short* h3T  = (unsigned short*)(ws + 2097152);   // 33554432
    float* out = (float*)d_out;

    const bool fused = (ws_size >= 35651584ull);

    hipLaunchKernelGGL(convert_kernel, dim3(1920), dim3(256), 0, stream,
                       tW2, tW3, bW1, bW2, bW3, bW4,
                       tW2T, tW3T, W1u, W2u, W3u, W4u);

    hipFuncSetAttribute(reinterpret_cast<const void*>(&mega_kernel),
                        hipFuncAttributeMaxDynamicSharedMemorySize, 149760);

    if (fused) {
        hipLaunchKernelGGL(mega_kernel, dim3(64 + 2048), dim3(512), 149760, stream,
                           64, 0, parameter, coords, W1u, bb1, W2u, bb2, W3u, bb3, W4u, bb4,
                           tW1, tb1, tW2T, tb2, tW3T, tb3, oW, ob, branch, h3T, out);
        hipLaunchKernelGGL(combine_kernel, dim3(256), dim3(512), 0, stream,
                           branch, oW, ob, h3T, out);
    } else {
        hipLaunchKernelGGL(mega_kernel, dim3(64), dim3(512), 149760, stream,
                           64, 1, parameter, coords, W1u, bb1, W2u, bb2, W3u, bb3, W4u, bb4,
                           tW1, tb1, tW2T, tb2, tW3T, tb3, oW, ob, branch, h3T, out);
        hipLaunchKernelGGL(mega_kernel, dim3(2048), dim3(512), 149760, stream,
                           0, 1, parameter, coords, W1u, bb1, W2u, bb2, W3u, bb3, W4u, bb4,
                           tW1, tb1, tW2T, tb2, tW3T, tb3, oW, ob, branch, h3T, out);
    }
}